// Round 26
// baseline (561.251 us; speedup 1.0000x reference)
//
#include <hip/hip_runtime.h>

#define Tn      8192
#define Cn      1024
#define En      8
#define Fn      2752
#define MAXROWS 18432
#define NT1     32      // Cn/32 K-tiles for gemm1
#define NT2     86      // Fn/32 K-tiles for gemm2

typedef __bf16 bf16;
typedef bf16  bf16x8 __attribute__((ext_vector_type(8)));
typedef bf16  bf16x4 __attribute__((ext_vector_type(4)));
typedef float f32x4  __attribute__((ext_vector_type(4)));

__device__ __forceinline__ void gload16(const bf16* g, bf16* l) {
  __builtin_amdgcn_global_load_lds(
      (const __attribute__((address_space(1))) unsigned int*)g,
      (__attribute__((address_space(3))) unsigned int*)l, 16, 0, 0);
}

#define BARRIER() __builtin_amdgcn_s_barrier()
#define VMCNT(N)  asm volatile("s_waitcnt vmcnt(" #N ")" ::: "memory")
#define MFMA(d, va, vb) d = __builtin_amdgcn_mfma_f32_16x16x32_bf16(va, vb, d, 0, 0, 0)

// bijective XCD-chunk swizzle: consecutive remapped ids land on the same XCD.
__device__ __forceinline__ int xcd_swz(int flat, int nwg) {
  int xcd = flat & 7, loc = flat >> 3;
  int q = nwg >> 3, r = nwg & 7;
  return (xcd < r ? xcd * (q + 1) : r * (q + 1) + (xcd - r) * q) + loc;
}

// ---------------- prep: gu transpose + gate (NO global atomics) + bf16 cast ---
__global__ __launch_bounds__(256) void prep_kernel(
    const float* __restrict__ wg, const float* __restrict__ wu,
    bf16* __restrict__ guT,
    const float* __restrict__ x, const float* __restrict__ wgate,
    int* __restrict__ topk_i, float* __restrict__ topk_w,
    bf16* __restrict__ xgd)
{
  const int id = blockIdx.x;
  if (id >= 11008) {
    // ---- gate + dense cast ----
    int lane = threadIdx.x & 63;
    int wid  = threadIdx.x >> 6;
    int t = (id - 11008) * 4 + wid;
    const float4* xr4 = (const float4*)(x + (size_t)t * Cn);
    bf16* xo = xgd + (size_t)t * Cn;
    float acc[En];
#pragma unroll
    for (int e = 0; e < En; ++e) acc[e] = 0.f;
#pragma unroll
    for (int i = 0; i < 4; ++i) {
      int c4 = i * 64 + lane;
      float4 xv = xr4[c4];
      bf16x4 pv;
      pv[0] = (bf16)xv.x; pv[1] = (bf16)xv.y; pv[2] = (bf16)xv.z; pv[3] = (bf16)xv.w;
      *(bf16x4*)(xo + c4 * 4) = pv;
#pragma unroll
      for (int e = 0; e < En; ++e) {
        const float4 wv = *(const float4*)(wgate + e * Cn + c4 * 4);
        acc[e] = fmaf(xv.x, wv.x, acc[e]);
        acc[e] = fmaf(xv.y, wv.y, acc[e]);
        acc[e] = fmaf(xv.z, wv.z, acc[e]);
        acc[e] = fmaf(xv.w, wv.w, acc[e]);
      }
    }
#pragma unroll
    for (int e = 0; e < En; ++e) {
#pragma unroll
      for (int o = 32; o > 0; o >>= 1) acc[e] += __shfl_xor(acc[e], o, 64);
    }
    if (lane == 0) {
      float mx = acc[0];
#pragma unroll
      for (int e = 1; e < En; ++e) mx = fmaxf(mx, acc[e]);
      float p[En], Z = 0.f;
#pragma unroll
      for (int e = 0; e < En; ++e) { p[e] = __expf(acc[e] - mx); Z += p[e]; }
      int i0 = 0;
#pragma unroll
      for (int e = 1; e < En; ++e) if (p[e] > p[i0]) i0 = e;
      int i1 = (i0 == 0) ? 1 : 0;
#pragma unroll
      for (int e = 0; e < En; ++e) if (e != i0 && p[e] > p[i1]) i1 = e;
      float s0 = p[i0] / Z, s1 = p[i1] / Z;
      float inv = 1.f / (s0 + s1 + 1e-9f);
      topk_i[2 * t] = i0;       topk_i[2 * t + 1] = i1;
      topk_w[2 * t] = s0 * inv; topk_w[2 * t + 1] = s1 * inv;
    }
    return;
  }
  // ---- gu transpose (proven body) ----
  int z = id / 688, rem = id % 688;
  const int bm = (rem % 16) * 64;        // C block
  const int bn = (rem / 16) * 64;        // F block
  const float* src = (z < En ? wg : wu) + (size_t)(z & 7) * Cn * Fn;
  bf16* dst = guT + (size_t)z * Cn * Fn;
  const int M = Cn, N = Fn;

  __shared__ float L[64][65];
  const int tid = threadIdx.x;
  const int mr = tid >> 4, nseg = tid & 15;
#pragma unroll
  for (int p = 0; p < 4; ++p) {
    int m = p * 16 + mr;
    float4 v = *(const float4*)(src + (size_t)(bm + m) * N + bn + nseg * 4);
    L[nseg * 4 + 0][m] = v.x;
    L[nseg * 4 + 1][m] = v.y;
    L[nseg * 4 + 2][m] = v.z;
    L[nseg * 4 + 3][m] = v.w;
  }
  __syncthreads();
  const int nr = tid >> 3, mseg = tid & 7;
#pragma unroll
  for (int q = 0; q < 2; ++q) {
    int n = q * 32 + nr;
    bf16x8 w;
#pragma unroll
    for (int j = 0; j < 8; ++j) w[j] = (bf16)L[n][mseg * 8 + j];
    *(bf16x8*)(dst + (size_t)(bn + n) * M + bm + mseg * 8) = w;
  }
}

// ---------------- offsets: histogram topk_i + prefix + padding init -----------
__global__ __launch_bounds__(256) void offsets_kernel(
    const int* __restrict__ topk_i, int* __restrict__ counts,
    int* __restrict__ fill, int* __restrict__ off, int* __restrict__ tok_list)
{
  __shared__ int lc[4][En];
  __shared__ int offl[En + 1];
  __shared__ int cntl[En];
  const int tid = threadIdx.x;
  const int w = tid >> 6;
  if (tid < 4 * En) lc[tid >> 3][tid & 7] = 0;
  __syncthreads();
  for (int i = tid; i < Tn * 2; i += 256)
    atomicAdd(&lc[w][topk_i[i]], 1);
  __syncthreads();
  if (tid == 0) {
    int o = 0;
    for (int e = 0; e < En; ++e) {
      int c = lc[0][e] + lc[1][e] + lc[2][e] + lc[3][e];
      cntl[e] = c;
      counts[e] = c;
      off[e]  = o;
      fill[e] = o;
      offl[e] = o;
      o += (c + 255) & ~255;             // 256-row expert padding
    }
    off[En] = o;
    offl[En] = o;
  }
  __syncthreads();
  for (int e = 0; e < En; ++e) {
    int lo = offl[e] + cntl[e], hi = offl[e + 1];
    for (int r = lo + tid; r < hi; r += 256) tok_list[r] = -1;
  }
}

// ---------------- scatter: block-aggregated (8 global atomics / block) --------
__global__ __launch_bounds__(256) void scatter_kernel(
    const int* __restrict__ topk_i, const float* __restrict__ topk_w,
    int* __restrict__ fill, int* __restrict__ tok_list, float* __restrict__ wgt_list,
    int* __restrict__ inv_rows)
{
  __shared__ int lc[En];
  __shared__ int base[En];
  const int tid = threadIdx.x;
  const int t = blockIdx.x * 256 + tid;
  if (tid < En) lc[tid] = 0;
  __syncthreads();
  int e0 = topk_i[2 * t], e1 = topk_i[2 * t + 1];
  int r0 = atomicAdd(&lc[e0], 1);
  int r1 = atomicAdd(&lc[e1], 1);
  __syncthreads();
  if (tid < En) base[tid] = atomicAdd(&fill[tid], lc[tid]);
  __syncthreads();
  int p0 = base[e0] + r0, p1 = base[e1] + r1;
  tok_list[p0] = t; wgt_list[p0] = topk_w[2 * t];     inv_rows[2 * t]     = p0;
  tok_list[p1] = t; wgt_list[p1] = topk_w[2 * t + 1]; inv_rows[2 * t + 1] = p1;
}

// A-tile LDS layout (BK=32, 64B rows = 4 x 16B slots):
//   LDS[row][slot] = G[row][slot ^ ((row>>1)&3)]   -> conflict-free b128 frag reads
// B frags are loaded DIRECTLY global->regs (natural layout, L2-resident):
//   b[ni] = wgT[e][n0+wnv+ni*16+fr][kt*32 + q*8 .. +8)  (16B/lane)

// ---------------- GEMM1 (B-from-global; + overlapped wd transpose) ------------
// blocks [0, ngemm): 256x64 gemm tiles, BK=32, 4 waves, A-only triple-buffered
//   48KB LDS (A issued 2 K-tiles ahead), B frags global->reg 1 K-tile ahead.
//   LDS reads/wave/K-tile: 12 -> 8 (the measured LDS-BW wall).
// blocks [ngemm, ngemm+5504): wd->wdT transpose (LDS aliased).
__global__ __launch_bounds__(256, 2) void gemm1_kernel(
    const bf16* __restrict__ xgd, const int* __restrict__ tok_list,
    const bf16* __restrict__ wgT, const bf16* __restrict__ wuT,
    const int* __restrict__ off, const int* __restrict__ counts,
    const float* __restrict__ wgt_list, bf16* __restrict__ h, int row_lo,
    const float* __restrict__ wd, bf16* __restrict__ wdT, int ngemm)
{
  __shared__ bf16 sm[3][8192];    // 48 KB: A tiles only (16KB per buffer)

  const int flat = blockIdx.x;
  const int tid = threadIdx.x;

  if (flat >= ngemm) {
    // ---- wd transpose path ----
    int id2 = flat - ngemm;
    int z = id2 / 688, rem = id2 % 688;
    const int bm = (rem % 43) * 64;      // F block
    const int bn = (rem / 43) * 64;      // C block
    const float* src = wd + (size_t)z * Fn * Cn;
    bf16* dst = wdT + (size_t)z * Fn * Cn;
    const int M = Fn, N = Cn;
    float (*L)[65] = reinterpret_cast<float(*)[65]>(&sm[0][0]);  // 16.6KB of 48KB

    const int mr = tid >> 4, nseg = tid & 15;
#pragma unroll
    for (int p = 0; p < 4; ++p) {
      int m = p * 16 + mr;
      float4 v = *(const float4*)(src + (size_t)(bm + m) * N + bn + nseg * 4);
      L[nseg * 4 + 0][m] = v.x;
      L[nseg * 4 + 1][m] = v.y;
      L[nseg * 4 + 2][m] = v.z;
      L[nseg * 4 + 3][m] = v.w;
    }
    __syncthreads();
    const int nr = tid >> 3, mseg = tid & 7;
#pragma unroll
    for (int q = 0; q < 2; ++q) {
      int n = q * 32 + nr;
      bf16x8 w;
#pragma unroll
      for (int j = 0; j < 8; ++j) w[j] = (bf16)L[n][mseg * 8 + j];
      *(bf16x8*)(dst + (size_t)(bn + n) * M + bm + mseg * 8) = w;
    }
    return;
  }

  // ---- gemm path ----
  const int gdx = 43;
  const int gdy = ngemm / 43;
  const int s = xcd_swz(flat, ngemm);
  int bx, by;
  if ((gdy & 7) == 0) {                      // m-fast within n-column, groups of 8
    const int gsz = gdx * 8;
    int grp = s / gsz, rem = s % gsz;
    bx = rem >> 3;
    by = grp * 8 + (rem & 7);
  } else { bx = s % gdx; by = s / gdx; }

  const int m0 = row_lo + by * 256;
  if (m0 >= off[En]) return;
  int e = 0;
  while (off[e + 1] <= m0) ++e;
  const int base = off[e], cnt = counts[e];
  const int n0 = bx * 64;

  const int lane = tid & 63, wid = tid >> 6;
  const int wm  = (wid & 1) * 128;        // wave m-half
  const int wnv = (wid >> 1) * 32;        // wave col-half (real F cols)
  const int fr = lane & 15, q = lane >> 4;
  const int lrow = tid >> 2;              // staging row 0..63
  const int gseg = (tid & 3) ^ ((tid >> 3) & 3);
  const int tt = (q ^ ((fr >> 1) & 3)) * 8;

  const bf16* wge = wgT + (size_t)e * ((size_t)Fn * Cn);
  const bf16* wue = wuT + (size_t)e * ((size_t)Fn * Cn);
  // per-lane indirect A bases (4 row-quarters)
  int tk0 = tok_list[m0 + lrow];        if (tk0 < 0) tk0 = 0;
  int tk1 = tok_list[m0 + 64 + lrow];   if (tk1 < 0) tk1 = 0;
  int tk2 = tok_list[m0 + 128 + lrow];  if (tk2 < 0) tk2 = 0;
  int tk3 = tok_list[m0 + 192 + lrow];  if (tk3 < 0) tk3 = 0;
  const bf16* ag0 = xgd + (size_t)tk0 * Cn + gseg * 8;
  const bf16* ag1 = xgd + (size_t)tk1 * Cn + gseg * 8;
  const bf16* ag2 = xgd + (size_t)tk2 * Cn + gseg * 8;
  const bf16* ag3 = xgd + (size_t)tk3 * Cn + gseg * 8;
  // per-lane B frag row pointers (natural layout; 16B at + kt*32)
  const bf16* pbg0 = wge + (size_t)(n0 + wnv +  0 + fr) * Cn + q * 8;
  const bf16* pbg1 = wge + (size_t)(n0 + wnv + 16 + fr) * Cn + q * 8;
  const bf16* pbu0 = wue + (size_t)(n0 + wnv +  0 + fr) * Cn + q * 8;
  const bf16* pbu1 = wue + (size_t)(n0 + wnv + 16 + fr) * Cn + q * 8;

  f32x4 accg[8][2], accu[8][2];
#pragma unroll
  for (int mi = 0; mi < 8; ++mi)
#pragma unroll
    for (int ni = 0; ni < 2; ++ni) { accg[mi][ni] = (f32x4)(0.f); accu[mi][ni] = (f32x4)(0.f); }

#define STG1(SRC, KOFF, DST, DOFF) gload16((SRC) + (KOFF), (DST) + (DOFF) + tid * 8)
#define ISSUE_A(DST, KO) do { \
    STG1(ag0, KO, DST, 0);    STG1(ag1, KO, DST, 2048); \
    STG1(ag2, KO, DST, 4096); STG1(ag3, KO, DST, 6144); } while (0)

  // prologue: b(0) regs (compiler-waited) + A(0),A(1) LDS; A(0) landed at vmcnt(4)
  bf16x8 bg0 = *(const bf16x8*)(pbg0);
  bf16x8 bg1 = *(const bf16x8*)(pbg1);
  bf16x8 bu0 = *(const bf16x8*)(pbu0);
  bf16x8 bu1 = *(const bf16x8*)(pbu1);
  ISSUE_A(&sm[0][0], 0);
  ISSUE_A(&sm[1][0], 32);
  VMCNT(4);
  BARRIER();

  const bf16* Sc = &sm[0][0];   // current (tile kt)
  const bf16* Sn = &sm[1][0];   // next    (tile kt+1, landing)
  bf16*       Sf = &sm[2][0];   // far     (tile kt+2, being issued)

  for (int kt = 0; kt < NT1; ++kt) {
    bf16x8 a[8];
#pragma unroll
    for (int mi = 0; mi < 8; ++mi)
      a[mi] = *(const bf16x8*)(Sc + (wm + mi * 16 + fr) * 32 + tt);

    __builtin_amdgcn_s_setprio(1);
#pragma unroll
    for (int mi = 0; mi < 8; ++mi) {
      MFMA(accg[mi][0], a[mi], bg0);
      MFMA(accg[mi][1], a[mi], bg1);
      MFMA(accu[mi][0], a[mi], bu0);
      MFMA(accu[mi][1], a[mi], bu1);
    }
    __builtin_amdgcn_s_setprio(0);

    // prefetch B(kt+1) into regs (after last use of B(kt))
    if (kt + 1 < NT1) {
      const int ko = (kt + 1) * 32;
      bg0 = *(const bf16x8*)(pbg0 + ko);
      bg1 = *(const bf16x8*)(pbg1 + ko);
      bu0 = *(const bf16x8*)(pbu0 + ko);
      bu1 = *(const bf16x8*)(pbu1 + ko);
    }
    // issue A(kt+2) into far buffer
    if (kt + 2 < NT1) ISSUE_A(Sf, (kt + 2) * 32);

    // ledger: newest 8 VMEM = {4 b(kt+1), 4 A(kt+2)}; vmcnt(8) => A(kt+1) landed.
    if (kt + 2 < NT1)      { VMCNT(8); BARRIER(); }
    else if (kt + 1 < NT1) { VMCNT(4); BARRIER(); }   // newest 4 = b(kt+1); A(kt+1) older -> done
    // rotate buffers
    const bf16* t0 = Sc; Sc = Sn; Sn = Sf; Sf = (bf16*)t0;
  }
#undef ISSUE_A
#undef STG1

  // epilogue: h = wgt * u * silu(g)
  const int rq = (lane >> 4) * 4, cl = lane & 15;
#pragma unroll
  for (int mi = 0; mi < 8; ++mi) {
#pragma unroll
    for (int r = 0; r < 4; ++r) {
      int grow = m0 + wm + mi * 16 + rq + r;
      float w = (grow - base < cnt) ? wgt_list[grow] : 0.f;
      bf16* hr = h + (size_t)(grow - row_lo) * Fn + n0;
#pragma unroll
      for (int ni = 0; ni < 2; ++ni) {
        float g = accg[mi][ni][r], u = accu[mi][ni][r];
        hr[wnv + ni * 16 + cl] = (bf16)(w * u * (g / (1.f + __expf(-g))));
      }
    }
  }
}

// ---------------- GEMM2: h2[row] = h[row] @ wdT' ------------------------------
// block 128m x 128n, BK=32, 256 thr / 4 waves (wave 64 x 64), dbuf 32KB,
// ~4 blocks/CU, grid 8n x (rows/128), m-fast-group-8 decode.
__global__ __launch_bounds__(256, 4) void gemm2_kernel(
    const bf16* __restrict__ h, const bf16* __restrict__ wdT,
    const int* __restrict__ off, bf16* __restrict__ h2, int row_lo)
{
  const int gdy = gridDim.y;                 // m-tiles (144)
  const int nwg = 8 * gdy;
  const int s = xcd_swz(blockIdx.y * 8 + blockIdx.x, nwg);
  int bn, bm;
  if ((gdy & 7) == 0) {
    int grp = s >> 6, rem = s & 63;          // gsz = 8 cols * 8 = 64
    bn = rem >> 3;
    bm = grp * 8 + (rem & 7);
  } else { bn = s & 7; bm = s >> 3; }

  const int m0 = row_lo + bm * 128;
  if (m0 >= off[En]) return;
  int e = 0;
  while (off[e + 1] <= m0) ++e;
  const int n0 = bn * 128;

  __shared__ bf16 sm[2][8192];               // 32 KB

  const int tid = threadIdx.x;
  const int lane = tid & 63, wid = tid >> 6;
  const int wrow = (wid & 1) * 64;
  const int wcol = (wid >> 1) * 64;
  const int fr = lane & 15, q = lane >> 4;
  const int lrow = tid >> 2;
  const int gseg = (tid & 3) ^ ((tid >> 3) & 3);
  const int tt = (q ^ ((fr >> 1) & 3)) * 8;

  const bf16* ap0 = h   + (size_t)(m0 - row_lo + lrow) * Fn + gseg * 8;
  const bf16* ap1 = ap0 + (size_t)64 * Fn;
  const bf16* bp0 = wdT + (size_t)e * Cn * Fn + (size_t)(n0 + lrow) * Fn + gseg * 8;
  const bf16* bp1 = bp0 + (size_t)64 * Fn;

  f32x4 acc[4][4];
#pragma unroll
  for (int mi = 0; mi < 4; ++mi)
#pragma unroll
    for (int ni = 0; ni < 4; ++ni) acc[mi][ni] = (f32x4)(0.f);

  {
    bf16* N = &sm[0][0];
    gload16(ap0, N + tid * 8);
    gload16(ap1, N + 2048 + tid * 8);
    gload16(bp0, N + 4096 + tid * 8);
    gload16(bp1, N + 6144 + tid * 8);
  }
  VMCNT(0);
  BARRIER();

  for (int kt = 0; kt < NT2; ++kt) {
    const bf16* S = &sm[kt & 1][0];
    bf16* Nx = &sm[(kt + 1) & 1][0];
    const int ko = (kt + 1) * 32;

    if (kt + 1 < NT2) {
      gload16(ap0 + ko, Nx + tid * 8);
      gload16(ap1 + ko, Nx + 2048 + tid * 8);
      gload16(bp0 + ko, Nx + 4096 + tid * 8);
      gload16(bp1 + ko, Nx + 6144 + tid * 8);
    }

    bf16x8 a[4], b[4];
#pragma unroll
    for (int mi = 0; mi < 4; ++mi)
      a[mi] = *(const bf16x8*)(S + (wrow + mi * 16 + fr) * 32 + tt);
#pragma unroll
    for (int ni = 0; ni < 4; ++ni)
      b[ni] = *(const bf16x8*)(S + 4096 + (wcol + ni * 16 + fr) * 32 + tt);

    __builtin_amdgcn_s_setprio(1);
#pragma unroll
    for (int mi = 0; mi < 4; ++mi)
#pragma unroll
      for (int ni = 0; ni < 4; ++ni)
        MFMA(acc[mi][ni], a[mi], b[ni]);
    __builtin_amdgcn_s_setprio(0);

    VMCNT(0);
    BARRIER();
  }

  const int rq = (lane >> 4) * 4, cl = lane & 15;
#pragma unroll
  for (int mi = 0; mi < 4; ++mi) {
#pragma unroll
    for (int r = 0; r < 4; ++r) {
      int grow = m0 + wrow + mi * 16 + rq + r;
      bf16* orow = h2 + (size_t)grow * Cn + n0;
#pragma unroll
      for (int ni = 0; ni < 4; ++ni)
        orow[wcol + ni * 16 + cl] = (bf16)acc[mi][ni][r];
    }
  }
}

// ---------------- combine: out[t] = h2[r0(t)] + h2[r1(t)] ---------------------
__global__ __launch_bounds__(256) void combine_kernel(
    const bf16* __restrict__ h2, const int* __restrict__ inv_rows,
    float* __restrict__ out)
{
  int t = blockIdx.x;
  int r0 = inv_rows[2 * t], r1 = inv_rows[2 * t + 1];
  int c = threadIdx.x * 4;
  bf16x4 a = *(const bf16x4*)(h2 + (size_t)r0 * Cn + c);
  bf16x4 b = *(const bf16x4*)(h2 + (size_t)r1 * Cn + c);
  float4 v;
  v.x = (float)a[0] + (float)b[0];
  v.y = (float)a[1] + (float)b[1];
  v.z = (float)a[2] + (float)b[2];
  v.w = (float)a[3] + (float)b[3];
  *(float4*)(out + (size_t)t * Cn + c) = v;
}

// ---------------- host launch ------------------------------------------------
extern "C" void kernel_launch(void* const* d_in, const int* in_sizes, int n_in,
                              void* d_out, int out_size, void* d_ws, size_t ws_size,
                              hipStream_t stream)
{
  const float* x     = (const float*)d_in[0];
  const float* wgate = (const float*)d_in[1];
  const float* wg    = (const float*)d_in[2];
  const float* wu    = (const float*)d_in[3];
  const float* wd    = (const float*)d_in[4];

  char* ws = (char*)d_ws;
  int* counts = (int*)ws;
  int* fill   = counts + 8;
  int* off    = fill + 8;
  size_t o = 256;
  int*   topk_i   = (int*)(ws + o);   o += (size_t)Tn * 2 * 4;
  float* topk_w   = (float*)(ws + o); o += (size_t)Tn * 2 * 4;
  int*   tok_list = (int*)(ws + o);   o += (size_t)MAXROWS * 4;
  float* wgt_list = (float*)(ws + o); o += (size_t)MAXROWS * 4;
  int*   inv_rows = (int*)(ws + o);   o += (size_t)Tn * 2 * 4;
  o = (o + 255) & ~(size_t)255;
  const size_t WSZ = (size_t)En * Fn * Cn;
  bf16* wgT = (bf16*)(ws + o); o += WSZ * 2 * 2;   // gu contiguous: wg then wu
  bf16* wuT = wgT + WSZ;
  bf16* wdT = (bf16*)(ws + o); o += WSZ * 2;
  bf16* xgd = (bf16*)(ws + o); o += (size_t)Tn * Cn * 2;   // dense bf16 x
  bf16* h2  = (bf16*)(ws + o); o += (size_t)MAXROWS * Cn * 2;
  bf16* h   = (bf16*)(ws + o);

  size_t havail = ws_size > o ? ws_size - o : 0;
  long crows = (long)(havail / ((size_t)Fn * 2));
  crows &= ~(long)255;
  if (crows > MAXROWS) crows = MAXROWS;
  if (crows < 256) crows = 256;
  const int chunk_rows = (int)crows;
  const int nch = (MAXROWS + chunk_rows - 1) / chunk_rows;

  prep_kernel<<<11008 + Tn / 4, 256, 0, stream>>>(
      wg, wu, wgT, x, wgate, topk_i, topk_w, xgd);

  offsets_kernel<<<1, 256, 0, stream>>>(topk_i, counts, fill, off, tok_list);
  scatter_kernel<<<Tn / 256, 256, 0, stream>>>(topk_i, topk_w, fill, tok_list, wgt_list, inv_rows);

  for (int c = 0; c < nch; ++c) {
    int row_lo = c * chunk_rows;
    const int ngemm = 43 * (chunk_rows / 256);
    const int nwd = (c == 0) ? 5504 : 0;     // wd transpose rides along once
    gemm1_kernel<<<ngemm + nwd, 256, 0, stream>>>(
        xgd, tok_list, wgT, wuT, off, counts, wgt_list, h, row_lo, wd, wdT, ngemm);
    gemm2_kernel<<<dim3(8, chunk_rows / 128), 256, 0, stream>>>(
        h, wdT, off, h2, row_lo);
  }
  combine_kernel<<<Tn, 256, 0, stream>>>(h2, inv_rows, (float*)d_out);
}

// Round 28
// 469.586 us; speedup vs baseline: 1.1952x; 1.1952x over previous
//
#include <hip/hip_runtime.h>

#define Tn      8192
#define Cn      1024
#define En      8
#define Fn      2752
#define MAXROWS 18432
#define NT1     32      // Cn/32 K-tiles for gemm1
#define NT2     86      // Fn/32 K-tiles for gemm2

typedef __bf16 bf16;
typedef bf16  bf16x8 __attribute__((ext_vector_type(8)));
typedef bf16  bf16x4 __attribute__((ext_vector_type(4)));
typedef float f32x4  __attribute__((ext_vector_type(4)));

__device__ __forceinline__ void gload16(const bf16* g, bf16* l) {
  __builtin_amdgcn_global_load_lds(
      (const __attribute__((address_space(1))) unsigned int*)g,
      (__attribute__((address_space(3))) unsigned int*)l, 16, 0, 0);
}

#define BARRIER() __builtin_amdgcn_s_barrier()
#define VMCNT(N)  asm volatile("s_waitcnt vmcnt(" #N ")" ::: "memory")
#define MFMA(d, va, vb) d = __builtin_amdgcn_mfma_f32_16x16x32_bf16(va, vb, d, 0, 0, 0)

// bijective XCD-chunk swizzle: consecutive remapped ids land on the same XCD.
__device__ __forceinline__ int xcd_swz(int flat, int nwg) {
  int xcd = flat & 7, loc = flat >> 3;
  int q = nwg >> 3, r = nwg & 7;
  return (xcd < r ? xcd * (q + 1) : r * (q + 1) + (xcd - r) * q) + loc;
}

// ---------------- prep: gu transpose + gate (NO global atomics) + bf16 cast ---
__global__ __launch_bounds__(256) void prep_kernel(
    const float* __restrict__ wg, const float* __restrict__ wu,
    bf16* __restrict__ guT,
    const float* __restrict__ x, const float* __restrict__ wgate,
    int* __restrict__ topk_i, float* __restrict__ topk_w,
    bf16* __restrict__ xgd)
{
  const int id = blockIdx.x;
  if (id >= 11008) {
    // ---- gate + dense cast ----
    int lane = threadIdx.x & 63;
    int wid  = threadIdx.x >> 6;
    int t = (id - 11008) * 4 + wid;
    const float4* xr4 = (const float4*)(x + (size_t)t * Cn);
    bf16* xo = xgd + (size_t)t * Cn;
    float acc[En];
#pragma unroll
    for (int e = 0; e < En; ++e) acc[e] = 0.f;
#pragma unroll
    for (int i = 0; i < 4; ++i) {
      int c4 = i * 64 + lane;
      float4 xv = xr4[c4];
      bf16x4 pv;
      pv[0] = (bf16)xv.x; pv[1] = (bf16)xv.y; pv[2] = (bf16)xv.z; pv[3] = (bf16)xv.w;
      *(bf16x4*)(xo + c4 * 4) = pv;
#pragma unroll
      for (int e = 0; e < En; ++e) {
        const float4 wv = *(const float4*)(wgate + e * Cn + c4 * 4);
        acc[e] = fmaf(xv.x, wv.x, acc[e]);
        acc[e] = fmaf(xv.y, wv.y, acc[e]);
        acc[e] = fmaf(xv.z, wv.z, acc[e]);
        acc[e] = fmaf(xv.w, wv.w, acc[e]);
      }
    }
#pragma unroll
    for (int e = 0; e < En; ++e) {
#pragma unroll
      for (int o = 32; o > 0; o >>= 1) acc[e] += __shfl_xor(acc[e], o, 64);
    }
    if (lane == 0) {
      float mx = acc[0];
#pragma unroll
      for (int e = 1; e < En; ++e) mx = fmaxf(mx, acc[e]);
      float p[En], Z = 0.f;
#pragma unroll
      for (int e = 0; e < En; ++e) { p[e] = __expf(acc[e] - mx); Z += p[e]; }
      int i0 = 0;
#pragma unroll
      for (int e = 1; e < En; ++e) if (p[e] > p[i0]) i0 = e;
      int i1 = (i0 == 0) ? 1 : 0;
#pragma unroll
      for (int e = 0; e < En; ++e) if (e != i0 && p[e] > p[i1]) i1 = e;
      float s0 = p[i0] / Z, s1 = p[i1] / Z;
      float inv = 1.f / (s0 + s1 + 1e-9f);
      topk_i[2 * t] = i0;       topk_i[2 * t + 1] = i1;
      topk_w[2 * t] = s0 * inv; topk_w[2 * t + 1] = s1 * inv;
    }
    return;
  }
  // ---- gu transpose (proven body) ----
  int z = id / 688, rem = id % 688;
  const int bm = (rem % 16) * 64;        // C block
  const int bn = (rem / 16) * 64;        // F block
  const float* src = (z < En ? wg : wu) + (size_t)(z & 7) * Cn * Fn;
  bf16* dst = guT + (size_t)z * Cn * Fn;
  const int M = Cn, N = Fn;

  __shared__ float L[64][65];
  const int tid = threadIdx.x;
  const int mr = tid >> 4, nseg = tid & 15;
#pragma unroll
  for (int p = 0; p < 4; ++p) {
    int m = p * 16 + mr;
    float4 v = *(const float4*)(src + (size_t)(bm + m) * N + bn + nseg * 4);
    L[nseg * 4 + 0][m] = v.x;
    L[nseg * 4 + 1][m] = v.y;
    L[nseg * 4 + 2][m] = v.z;
    L[nseg * 4 + 3][m] = v.w;
  }
  __syncthreads();
  const int nr = tid >> 3, mseg = tid & 7;
#pragma unroll
  for (int q = 0; q < 2; ++q) {
    int n = q * 32 + nr;
    bf16x8 w;
#pragma unroll
    for (int j = 0; j < 8; ++j) w[j] = (bf16)L[n][mseg * 8 + j];
    *(bf16x8*)(dst + (size_t)(bn + n) * M + bm + mseg * 8) = w;
  }
}

// ---------------- offsets: histogram topk_i + prefix + padding init -----------
__global__ __launch_bounds__(256) void offsets_kernel(
    const int* __restrict__ topk_i, int* __restrict__ counts,
    int* __restrict__ fill, int* __restrict__ off, int* __restrict__ tok_list)
{
  __shared__ int lc[4][En];
  __shared__ int offl[En + 1];
  __shared__ int cntl[En];
  const int tid = threadIdx.x;
  const int w = tid >> 6;
  if (tid < 4 * En) lc[tid >> 3][tid & 7] = 0;
  __syncthreads();
  for (int i = tid; i < Tn * 2; i += 256)
    atomicAdd(&lc[w][topk_i[i]], 1);
  __syncthreads();
  if (tid == 0) {
    int o = 0;
    for (int e = 0; e < En; ++e) {
      int c = lc[0][e] + lc[1][e] + lc[2][e] + lc[3][e];
      cntl[e] = c;
      counts[e] = c;
      off[e]  = o;
      fill[e] = o;
      offl[e] = o;
      o += (c + 255) & ~255;             // 256-row expert padding
    }
    off[En] = o;
    offl[En] = o;
  }
  __syncthreads();
  for (int e = 0; e < En; ++e) {
    int lo = offl[e] + cntl[e], hi = offl[e + 1];
    for (int r = lo + tid; r < hi; r += 256) tok_list[r] = -1;
  }
}

// ---------------- scatter: block-aggregated (8 global atomics / block) --------
__global__ __launch_bounds__(256) void scatter_kernel(
    const int* __restrict__ topk_i, const float* __restrict__ topk_w,
    int* __restrict__ fill, int* __restrict__ tok_list, float* __restrict__ wgt_list,
    int* __restrict__ inv_rows)
{
  __shared__ int lc[En];
  __shared__ int base[En];
  const int tid = threadIdx.x;
  const int t = blockIdx.x * 256 + tid;
  if (tid < En) lc[tid] = 0;
  __syncthreads();
  int e0 = topk_i[2 * t], e1 = topk_i[2 * t + 1];
  int r0 = atomicAdd(&lc[e0], 1);
  int r1 = atomicAdd(&lc[e1], 1);
  __syncthreads();
  if (tid < En) base[tid] = atomicAdd(&fill[tid], lc[tid]);
  __syncthreads();
  int p0 = base[e0] + r0, p1 = base[e1] + r1;
  tok_list[p0] = t; wgt_list[p0] = topk_w[2 * t];     inv_rows[2 * t]     = p0;
  tok_list[p1] = t; wgt_list[p1] = topk_w[2 * t + 1]; inv_rows[2 * t + 1] = p1;
}

// LDS K-tile layout (BK=32, 64B rows = 4 x 16B slots):
//   LDS[row][slot] = G[row][slot ^ ((row>>1)&3)]   -> conflict-free b128 frag reads
// staging lane: row = tid>>2, gseg = (tid&3) ^ ((tid>>3)&3)
// frag read:   slot = q ^ ((fr>>1)&3),  q = lane>>4, fr = lane&15

// ---------------- GEMM1 (+ overlapped wd transpose) ---------------------------
// blocks [0, ngemm): 256x64 gemm tiles (BK=32, 4 waves, triple-buffered 72KB,
//   loads 2 K-tiles ahead, m-fast-group-8 decode, indirect A via tok_list).
// blocks [ngemm, ngemm+5504): wd->wdT transpose (LDS aliased into sm).
// wdT is first READ by gemm2, which launches after this kernel completes.
__global__ __launch_bounds__(256, 2) void gemm1_kernel(
    const bf16* __restrict__ xgd, const int* __restrict__ tok_list,
    const bf16* __restrict__ wgT, const bf16* __restrict__ wuT,
    const int* __restrict__ off, const int* __restrict__ counts,
    const float* __restrict__ wgt_list, bf16* __restrict__ h, int row_lo,
    const float* __restrict__ wd, bf16* __restrict__ wdT, int ngemm)
{
  __shared__ bf16 sm[3][12288];   // 72 KB (gemm buffers; aliased by transpose)

  const int flat = blockIdx.x;
  const int tid = threadIdx.x;

  if (flat >= ngemm) {
    // ---- wd transpose path ----
    int id2 = flat - ngemm;
    int z = id2 / 688, rem = id2 % 688;
    const int bm = (rem % 43) * 64;      // F block
    const int bn = (rem / 43) * 64;      // C block
    const float* src = wd + (size_t)z * Fn * Cn;
    bf16* dst = wdT + (size_t)z * Fn * Cn;
    const int M = Fn, N = Cn;
    float (*L)[65] = reinterpret_cast<float(*)[65]>(&sm[0][0]);  // 16.6KB of 72KB

    const int mr = tid >> 4, nseg = tid & 15;
#pragma unroll
    for (int p = 0; p < 4; ++p) {
      int m = p * 16 + mr;
      float4 v = *(const float4*)(src + (size_t)(bm + m) * N + bn + nseg * 4);
      L[nseg * 4 + 0][m] = v.x;
      L[nseg * 4 + 1][m] = v.y;
      L[nseg * 4 + 2][m] = v.z;
      L[nseg * 4 + 3][m] = v.w;
    }
    __syncthreads();
    const int nr = tid >> 3, mseg = tid & 7;
#pragma unroll
    for (int q = 0; q < 2; ++q) {
      int n = q * 32 + nr;
      bf16x8 w;
#pragma unroll
      for (int j = 0; j < 8; ++j) w[j] = (bf16)L[n][mseg * 8 + j];
      *(bf16x8*)(dst + (size_t)(bn + n) * M + bm + mseg * 8) = w;
    }
    return;
  }

  // ---- gemm path ----
  const int gdx = 43;
  const int gdy = ngemm / 43;
  const int s = xcd_swz(flat, ngemm);
  int bx, by;
  if ((gdy & 7) == 0) {                      // m-fast within n-column, groups of 8
    const int gsz = gdx * 8;
    int grp = s / gsz, rem = s % gsz;
    bx = rem >> 3;
    by = grp * 8 + (rem & 7);
  } else { bx = s % gdx; by = s / gdx; }

  const int m0 = row_lo + by * 256;
  if (m0 >= off[En]) return;
  int e = 0;
  while (off[e + 1] <= m0) ++e;
  const int base = off[e], cnt = counts[e];
  const int n0 = bx * 64;

  const int lane = tid & 63, wid = tid >> 6;
  const int wm  = (wid & 1) * 128;        // wave m-half
  const int wnv = (wid >> 1) * 32;        // wave col-half (real F cols)
  const int fr = lane & 15, q = lane >> 4;
  const int lrow = tid >> 2;              // staging row 0..63
  const int gseg = (tid & 3) ^ ((tid >> 3) & 3);
  const int tt = (q ^ ((fr >> 1) & 3)) * 8;

  const bf16* wge = wgT + (size_t)e * ((size_t)Fn * Cn);
  const bf16* wue = wuT + (size_t)e * ((size_t)Fn * Cn);
  // per-lane indirect A bases (4 row-quarters)
  int tk0 = tok_list[m0 + lrow];        if (tk0 < 0) tk0 = 0;
  int tk1 = tok_list[m0 + 64 + lrow];   if (tk1 < 0) tk1 = 0;
  int tk2 = tok_list[m0 + 128 + lrow];  if (tk2 < 0) tk2 = 0;
  int tk3 = tok_list[m0 + 192 + lrow];  if (tk3 < 0) tk3 = 0;
  const bf16* ag0 = xgd + (size_t)tk0 * Cn + gseg * 8;
  const bf16* ag1 = xgd + (size_t)tk1 * Cn + gseg * 8;
  const bf16* ag2 = xgd + (size_t)tk2 * Cn + gseg * 8;
  const bf16* ag3 = xgd + (size_t)tk3 * Cn + gseg * 8;
  const bf16* bgp = wge + (size_t)(n0 + lrow) * Cn + gseg * 8;
  const bf16* bup = wue + (size_t)(n0 + lrow) * Cn + gseg * 8;

  f32x4 accg[8][2], accu[8][2];
#pragma unroll
  for (int mi = 0; mi < 8; ++mi)
#pragma unroll
    for (int ni = 0; ni < 2; ++ni) { accg[mi][ni] = (f32x4)(0.f); accu[mi][ni] = (f32x4)(0.f); }

#define STG1(SRC, KOFF, DST, DOFF) gload16((SRC) + (KOFF), (DST) + (DOFF) + tid * 8)
#define ISSUE1(DST, KO) do { \
    STG1(ag0, KO, DST, 0);    STG1(ag1, KO, DST, 2048); \
    STG1(ag2, KO, DST, 4096); STG1(ag3, KO, DST, 6144); \
    STG1(bgp, KO, DST, 8192); STG1(bup, KO, DST, 10240); } while (0)

  // prologue: issue tiles 0 and 1; wait tile 0 (6 of tile 1 in flight)
  ISSUE1(&sm[0][0], 0);
  ISSUE1(&sm[1][0], 32);
  VMCNT(6);
  BARRIER();

  const bf16* Sc = &sm[0][0];   // current (tile kt)
  const bf16* Sn = &sm[1][0];   // next    (tile kt+1, landing)
  bf16*       Sf = &sm[2][0];   // far     (tile kt+2, being issued)

  for (int kt = 0; kt < NT1; ++kt) {
    bf16x8 a[8], bg[2], bu[2];
#pragma unroll
    for (int mi = 0; mi < 8; ++mi)
      a[mi] = *(const bf16x8*)(Sc + (wm + mi * 16 + fr) * 32 + tt);
#pragma unroll
    for (int ni = 0; ni < 2; ++ni) {
      bg[ni] = *(const bf16x8*)(Sc + 8192 + (wnv + ni * 16 + fr) * 32 + tt);
      bu[ni] = *(const bf16x8*)(Sc + 10240 + (wnv + ni * 16 + fr) * 32 + tt);
    }
    if (kt + 2 < NT1) ISSUE1(Sf, (kt + 2) * 32);

    __builtin_amdgcn_s_setprio(1);
#pragma unroll
    for (int mi = 0; mi < 8; ++mi)
#pragma unroll
      for (int ni = 0; ni < 2; ++ni) {
        MFMA(accg[mi][ni], a[mi], bg[ni]);
        MFMA(accu[mi][ni], a[mi], bu[ni]);
      }
    __builtin_amdgcn_s_setprio(0);

    if (kt < NT1 - 2)       { VMCNT(6); BARRIER(); }
    else if (kt == NT1 - 2) { VMCNT(0); BARRIER(); }
    // rotate buffers
    const bf16* t0 = Sc; Sc = Sn; Sn = Sf; Sf = (bf16*)t0;
  }
#undef ISSUE1
#undef STG1

  // epilogue: h = wgt * u * silu(g)
  const int rq = (lane >> 4) * 4, cl = lane & 15;
#pragma unroll
  for (int mi = 0; mi < 8; ++mi) {
#pragma unroll
    for (int r = 0; r < 4; ++r) {
      int grow = m0 + wm + mi * 16 + rq + r;
      float w = (grow - base < cnt) ? wgt_list[grow] : 0.f;
      bf16* hr = h + (size_t)(grow - row_lo) * Fn + n0;
#pragma unroll
      for (int ni = 0; ni < 2; ++ni) {
        float g = accg[mi][ni][r], u = accu[mi][ni][r];
        hr[wnv + ni * 16 + cl] = (bf16)(w * u * (g / (1.f + __expf(-g))));
      }
    }
  }
}

// ---------------- GEMM2: h2[row] = h[row] @ wdT' ------------------------------
// block 128m x 128n, BK=32, 256 thr / 4 waves (wave 64 x 64), dbuf 32KB,
// ~4 blocks/CU, grid 8n x (rows/128), m-fast-group-8 decode.
__global__ __launch_bounds__(256, 4) void gemm2_kernel(
    const bf16* __restrict__ h, const bf16* __restrict__ wdT,
    const int* __restrict__ off, bf16* __restrict__ h2, int row_lo)
{
  const int gdy = gridDim.y;                 // m-tiles (144)
  const int nwg = 8 * gdy;
  const int s = xcd_swz(blockIdx.y * 8 + blockIdx.x, nwg);
  int bn, bm;
  if ((gdy & 7) == 0) {
    int grp = s >> 6, rem = s & 63;          // gsz = 8 cols * 8 = 64
    bn = rem >> 3;
    bm = grp * 8 + (rem & 7);
  } else { bn = s & 7; bm = s >> 3; }

  const int m0 = row_lo + bm * 128;
  if (m0 >= off[En]) return;
  int e = 0;
  while (off[e + 1] <= m0) ++e;
  const int n0 = bn * 128;

  __shared__ bf16 sm[2][8192];               // 32 KB

  const int tid = threadIdx.x;
  const int lane = tid & 63, wid = tid >> 6;
  const int wrow = (wid & 1) * 64;
  const int wcol = (wid >> 1) * 64;
  const int fr = lane & 15, q = lane >> 4;
  const int lrow = tid >> 2;
  const int gseg = (tid & 3) ^ ((tid >> 3) & 3);
  const int tt = (q ^ ((fr >> 1) & 3)) * 8;

  const bf16* ap0 = h   + (size_t)(m0 - row_lo + lrow) * Fn + gseg * 8;
  const bf16* ap1 = ap0 + (size_t)64 * Fn;
  const bf16* bp0 = wdT + (size_t)e * Cn * Fn + (size_t)(n0 + lrow) * Fn + gseg * 8;
  const bf16* bp1 = bp0 + (size_t)64 * Fn;

  f32x4 acc[4][4];
#pragma unroll
  for (int mi = 0; mi < 4; ++mi)
#pragma unroll
    for (int ni = 0; ni < 4; ++ni) acc[mi][ni] = (f32x4)(0.f);

  {
    bf16* N = &sm[0][0];
    gload16(ap0, N + tid * 8);
    gload16(ap1, N + 2048 + tid * 8);
    gload16(bp0, N + 4096 + tid * 8);
    gload16(bp1, N + 6144 + tid * 8);
  }
  VMCNT(0);
  BARRIER();

  for (int kt = 0; kt < NT2; ++kt) {
    const bf16* S = &sm[kt & 1][0];
    bf16* Nx = &sm[(kt + 1) & 1][0];
    const int ko = (kt + 1) * 32;

    if (kt + 1 < NT2) {
      gload16(ap0 + ko, Nx + tid * 8);
      gload16(ap1 + ko, Nx + 2048 + tid * 8);
      gload16(bp0 + ko, Nx + 4096 + tid * 8);
      gload16(bp1 + ko, Nx + 6144 + tid * 8);
    }

    bf16x8 a[4], b[4];
#pragma unroll
    for (int mi = 0; mi < 4; ++mi)
      a[mi] = *(const bf16x8*)(S + (wrow + mi * 16 + fr) * 32 + tt);
#pragma unroll
    for (int ni = 0; ni < 4; ++ni)
      b[ni] = *(const bf16x8*)(S + 4096 + (wcol + ni * 16 + fr) * 32 + tt);

    __builtin_amdgcn_s_setprio(1);
#pragma unroll
    for (int mi = 0; mi < 4; ++mi)
#pragma unroll
      for (int ni = 0; ni < 4; ++ni)
        MFMA(acc[mi][ni], a[mi], b[ni]);
    __builtin_amdgcn_s_setprio(0);

    VMCNT(0);
    BARRIER();
  }

  const int rq = (lane >> 4) * 4, cl = lane & 15;
#pragma unroll
  for (int mi = 0; mi < 4; ++mi) {
#pragma unroll
    for (int r = 0; r < 4; ++r) {
      int grow = m0 + wrow + mi * 16 + rq + r;
      bf16* orow = h2 + (size_t)grow * Cn + n0;
#pragma unroll
      for (int ni = 0; ni < 4; ++ni)
        orow[wcol + ni * 16 + cl] = (bf16)acc[mi][ni][r];
    }
  }
}

// ---------------- combine: out[t] = h2[r0(t)] + h2[r1(t)] ---------------------
__global__ __launch_bounds__(256) void combine_kernel(
    const bf16* __restrict__ h2, const int* __restrict__ inv_rows,
    float* __restrict__ out)
{
  int t = blockIdx.x;
  int r0 = inv_rows[2 * t], r1 = inv_rows[2 * t + 1];
  int c = threadIdx.x * 4;
  bf16x4 a = *(const bf16x4*)(h2 + (size_t)r0 * Cn + c);
  bf16x4 b = *(const bf16x4*)(h2 + (size_t)r1 * Cn + c);
  float4 v;
  v.x = (float)a[0] + (float)b[0];
  v.y = (float)a[1] + (float)b[1];
  v.z = (float)a[2] + (float)b[2];
  v.w = (float)a[3] + (float)b[3];
  *(float4*)(out + (size_t)t * Cn + c) = v;
}

// ---------------- host launch ------------------------------------------------
extern "C" void kernel_launch(void* const* d_in, const int* in_sizes, int n_in,
                              void* d_out, int out_size, void* d_ws, size_t ws_size,
                              hipStream_t stream)
{
  const float* x     = (const float*)d_in[0];
  const float* wgate = (const float*)d_in[1];
  const float* wg    = (const float*)d_in[2];
  const float* wu    = (const float*)d_in[3];
  const float* wd    = (const float*)d_in[4];

  char* ws = (char*)d_ws;
  int* counts = (int*)ws;
  int* fill   = counts + 8;
  int* off    = fill + 8;
  size_t o = 256;
  int*   topk_i   = (int*)(ws + o);   o += (size_t)Tn * 2 * 4;
  float* topk_w   = (float*)(ws + o); o += (size_t)Tn * 2 * 4;
  int*   tok_list = (int*)(ws + o);   o += (size_t)MAXROWS * 4;
  float* wgt_list = (float*)(ws + o); o += (size_t)MAXROWS * 4;
  int*   inv_rows = (int*)(ws + o);   o += (size_t)Tn * 2 * 4;
  o = (o + 255) & ~(size_t)255;
  const size_t WSZ = (size_t)En * Fn * Cn;
  bf16* wgT = (bf16*)(ws + o); o += WSZ * 2 * 2;   // gu contiguous: wg then wu
  bf16* wuT = wgT + WSZ;
  bf16* wdT = (bf16*)(ws + o); o += WSZ * 2;
  bf16* xgd = (bf16*)(ws + o); o += (size_t)Tn * Cn * 2;   // dense bf16 x
  bf16* h2  = (bf16*)(ws + o); o += (size_t)MAXROWS * Cn * 2;
  bf16* h   = (bf16*)(ws + o);

  size_t havail = ws_size > o ? ws_size - o : 0;
  long crows = (long)(havail / ((size_t)Fn * 2));
  crows &= ~(long)255;
  if (crows > MAXROWS) crows = MAXROWS;
  if (crows < 256) crows = 256;
  const int chunk_rows = (int)crows;
  const int nch = (MAXROWS + chunk_rows - 1) / chunk_rows;

  prep_kernel<<<11008 + Tn / 4, 256, 0, stream>>>(
      wg, wu, wgT, x, wgate, topk_i, topk_w, xgd);

  offsets_kernel<<<1, 256, 0, stream>>>(topk_i, counts, fill, off, tok_list);
  scatter_kernel<<<Tn / 256, 256, 0, stream>>>(topk_i, topk_w, fill, tok_list, wgt_list, inv_rows);

  for (int c = 0; c < nch; ++c) {
    int row_lo = c * chunk_rows;
    const int ngemm = 43 * (chunk_rows / 256);
    const int nwd = (c == 0) ? 5504 : 0;     // wd transpose rides along once
    gemm1_kernel<<<ngemm + nwd, 256, 0, stream>>>(
        xgd, tok_list, wgT, wuT, off, counts, wgt_list, h, row_lo, wd, wdT, ngemm);
    gemm2_kernel<<<dim3(8, chunk_rows / 128), 256, 0, stream>>>(
        h, wdT, off, h2, row_lo);
  }
  combine_kernel<<<Tn, 256, 0, stream>>>(h2, inv_rows, (float*)d_out);
}